// Round 11
// baseline (231.609 us; speedup 1.0000x reference)
//
#include <hip/hip_runtime.h>
#include <hip/hip_bf16.h>
#include <math.h>

#define DMODEL 1024
#define NHEAD  16
#define DHEAD  64
#define BATCH  2
#define SEQ    2048
#define MROWS  (BATCH * SEQ)   // 4096

typedef __attribute__((ext_vector_type(8))) __bf16 bf16x8;
typedef __attribute__((ext_vector_type(4))) float  f32x4;

// async global->LDS, 16 B per lane. LDS dest must be wave-uniform base + lane*16.
__device__ __forceinline__ void load16_lds(const ushort* g, ushort* l) {
    __builtin_amdgcn_global_load_lds(
        (const __attribute__((address_space(1))) unsigned int*)g,
        (__attribute__((address_space(3))) unsigned int*)l, 16, 0, 0);
}

__device__ __forceinline__ ushort bf16u(float v) {
    __hip_bfloat16 h = __float2bfloat16(v);
    return *reinterpret_cast<ushort*>(&h);
}

// ---------------------------------------------------------------------------
// prep: one kernel for rope table + x cast + 4 weight casts (saves launches).
// blocks [0,256): tab; [256,2304): x; [2304,4352): weights (512 each).
// ---------------------------------------------------------------------------
__global__ __launch_bounds__(256)
void prep(const float* __restrict__ x,
          const float* __restrict__ w0, const float* __restrict__ w1,
          const float* __restrict__ w2, const float* __restrict__ w3,
          const int* __restrict__ pos,
          ushort* __restrict__ xb, ushort* __restrict__ wdst,
          float2* __restrict__ tab) {
    const int blk = blockIdx.x;
    const int tid = threadIdx.x;
    if (blk < 256) {
        const int idx = blk * 256 + tid;          // 0..65535
        const int s = idx >> 5;
        const int i = idx & 31;
        const float p = (float)pos[s];
        const float inv = exp2f(-(float)i * 0.41524101186092f);  // 2*log2(1e4)/64
        float sn, cs;
        sincosf(p * inv, &sn, &cs);
        tab[idx] = make_float2(cs, sn);
    } else if (blk < 2304) {
        const int i = ((blk - 256) * 256 + tid) * 8;
        const f32x4 a = *reinterpret_cast<const f32x4*>(x + i);
        const f32x4 b = *reinterpret_cast<const f32x4*>(x + i + 4);
        bf16x8 o;
        #pragma unroll
        for (int j = 0; j < 4; j++) { o[j] = (__bf16)a[j]; o[4 + j] = (__bf16)b[j]; }
        *reinterpret_cast<bf16x8*>(xb + i) = o;
    } else {
        const int bi = blk - 2304;
        const int which = bi >> 9;                // 512 blocks per weight
        const float* src = (which == 0) ? w0 : (which == 1) ? w1
                         : (which == 2) ? w2 : w3;
        const int i = ((bi & 511) * 256 + tid) * 8;
        const f32x4 a = *reinterpret_cast<const f32x4*>(src + i);
        const f32x4 b = *reinterpret_cast<const f32x4*>(src + i + 4);
        bf16x8 o;
        #pragma unroll
        for (int j = 0; j < 4; j++) { o[j] = (__bf16)a[j]; o[4 + j] = (__bf16)b[j]; }
        *reinterpret_cast<bf16x8*>(wdst + (size_t)which * DMODEL * DMODEL + i) = o;
    }
}

// ---------------------------------------------------------------------------
// Fused QKV GEMM, double-buffered (one barrier per K-tile).
// n>>10: 0 -> q [b,h,s,dh] (+RoPE fused), 1 -> k (+RoPE), 2 -> V^T.
// ---------------------------------------------------------------------------
__global__ __launch_bounds__(256)
void gemm_qkv(const ushort* __restrict__ A, const ushort* __restrict__ B,
              ushort* __restrict__ C, const float2* __restrict__ tab) {
    __shared__ __align__(16) ushort pool[16384];   // 32 KB: As[2][4096] Bs[2][4096]
    ushort* As = pool;
    ushort* Bs = pool + 8192;
    const int tid  = threadIdx.x;
    const int m0   = blockIdx.y * 128;
    const int n0   = blockIdx.x * 128;
    const int lane = tid & 63;
    const int w    = tid >> 6;
    const int l16  = lane & 15;
    const int quad = lane >> 4;
    const int wm   = (w >> 1) * 64;
    const int wn   = (w & 1) * 64;
    const int srow = tid >> 2;
    const int scol = (tid & 3) * 8;

    f32x4 acc[4][4];
    #pragma unroll
    for (int i = 0; i < 4; i++)
        #pragma unroll
        for (int j = 0; j < 4; j++) acc[i][j] = (f32x4){0.f, 0.f, 0.f, 0.f};

    #pragma unroll
    for (int half = 0; half < 2; half++) {
        const int row = srow + half * 64;
        load16_lds(A + (size_t)(m0 + row) * DMODEL + scol, &As[row * 32 + scol]);
        load16_lds(B + (size_t)(n0 + row) * DMODEL + scol, &Bs[row * 32 + scol]);
    }

    for (int t = 0; t < 32; t++) {
        const int bf = t & 1;
        __syncthreads();
        if (t + 1 < 32) {
            const int k0 = (t + 1) * 32;
            const int o  = (bf ^ 1) * 4096;
            #pragma unroll
            for (int half = 0; half < 2; half++) {
                const int row = srow + half * 64;
                load16_lds(A + (size_t)(m0 + row) * DMODEL + k0 + scol,
                           &As[o + row * 32 + scol]);
                load16_lds(B + (size_t)(n0 + row) * DMODEL + k0 + scol,
                           &Bs[o + row * 32 + scol]);
            }
        }
        const int o = bf * 4096;
        bf16x8 af[4], bfr[4];
        #pragma unroll
        for (int s = 0; s < 4; s++)
            af[s] = *reinterpret_cast<const bf16x8*>(
                &As[o + (wm + s * 16 + l16) * 32 + quad * 8]);
        #pragma unroll
        for (int s = 0; s < 4; s++)
            bfr[s] = *reinterpret_cast<const bf16x8*>(
                &Bs[o + (wn + s * 16 + l16) * 32 + quad * 8]);
        #pragma unroll
        for (int i = 0; i < 4; i++)
            #pragma unroll
            for (int j = 0; j < 4; j++)
                acc[i][j] = __builtin_amdgcn_mfma_f32_16x16x32_bf16(
                    af[i], bfr[j], acc[i][j], 0, 0, 0);
    }

    const int nbase  = n0 + wn;
    const int tensor = nbase >> 10;        // block-uniform
    const int hh     = (nbase & 1023) >> 6;
    if (tensor < 2) {
        ushort* Dt = C + (size_t)tensor * ((size_t)MROWS * DMODEL);
        #pragma unroll
        for (int i = 0; i < 4; i++)
            #pragma unroll
            for (int r = 0; r < 4; r++) {
                const int m  = m0 + wm + i * 16 + quad * 4 + r;
                const int bb = m >> 11;
                const int ss = m & (SEQ - 1);
                const float2* trow = tab + ss * 32;
                #pragma unroll
                for (int j = 0; j < 4; j++) {
                    const int f = j * 16 + l16;          // dh 0..63
                    const float2 cs = trow[f >> 1];
                    const float val = acc[i][j][r];
                    const float prt = __shfl_xor(val, 1, 64);
                    const float out = (f & 1) ? (prt * cs.y + val * cs.x)
                                              : (val * cs.x - prt * cs.y);
                    Dt[(((size_t)(bb * NHEAD + hh)) * SEQ + ss) * DHEAD + f] =
                        bf16u(out);
                }
            }
    } else {
        __syncthreads();   // all MFMA LDS reads done; safe to overlay pool
        ushort* Tw = pool + w * 4096;   // 8 KB per wave
        #pragma unroll
        for (int i = 0; i < 4; i++)
            #pragma unroll
            for (int j = 0; j < 4; j++) {
                const int f = j * 16 + l16;
                #pragma unroll
                for (int r = 0; r < 4; r++) {
                    const int ml = i * 16 + quad * 4 + r;
                    Tw[f * 64 + (ml ^ ((f & 7) << 3))] = bf16u(acc[i][j][r]);
                }
            }
        ushort* Dv = C + 2 * ((size_t)MROWS * DMODEL);
        const int c  = lane & 7;
        const int fb = lane >> 3;
        #pragma unroll
        for (int rr = 0; rr < 8; rr++) {
            const int fl = rr * 8 + fb;
            const uint4 v = *reinterpret_cast<const uint4*>(
                &Tw[fl * 64 + ((c << 3) ^ ((fl & 7) << 3))]);
            *reinterpret_cast<uint4*>(
                &Dv[(size_t)(hh * 64 + fl) * MROWS + m0 + wm + (c << 3)]) = v;
        }
    }
}

// ---------------------------------------------------------------------------
// Output GEMM, 64x128 tile, double-buffered. A in [b,h,s,dh], f32 out.
// ---------------------------------------------------------------------------
__global__ __launch_bounds__(256)
void gemm_out64(const ushort* __restrict__ A, const ushort* __restrict__ B,
                float* __restrict__ C) {
    __shared__ __align__(16) ushort pool[12288];   // As[2][2048] Bs[2][4096]
    ushort* As = pool;
    ushort* Bs = pool + 4096;
    const int tid  = threadIdx.x;
    const int m0   = blockIdx.y * 64;
    const int n0   = blockIdx.x * 128;
    const int lane = tid & 63;
    const int w    = tid >> 6;
    const int l16  = lane & 15;
    const int quad = lane >> 4;
    const int wm   = (w >> 1) * 32;
    const int wn   = (w & 1) * 64;
    const int srow = tid >> 2;
    const int scol = (tid & 3) * 8;

    const int am  = m0 + srow;
    const int abb = am >> 11;
    const int ass = am & (SEQ - 1);
    const size_t abase = ((size_t)(abb * NHEAD)) * SEQ * DHEAD + (size_t)ass * DHEAD;

    f32x4 acc[2][4];
    #pragma unroll
    for (int i = 0; i < 2; i++)
        #pragma unroll
        for (int j = 0; j < 4; j++) acc[i][j] = (f32x4){0.f, 0.f, 0.f, 0.f};

    {
        const int h = scol >> 6, dh = scol & 63;
        load16_lds(A + abase + (size_t)h * SEQ * DHEAD + dh, &As[srow * 32 + scol]);
        #pragma unroll
        for (int half = 0; half < 2; half++) {
            const int row = srow + half * 64;
            load16_lds(B + (size_t)(n0 + row) * DMODEL + scol, &Bs[row * 32 + scol]);
        }
    }

    for (int t = 0; t < 32; t++) {
        const int bf = t & 1;
        __syncthreads();
        if (t + 1 < 32) {
            const int k0 = (t + 1) * 32;
            const int kk = k0 + scol;
            const int h = kk >> 6, dh = kk & 63;
            load16_lds(A + abase + (size_t)h * SEQ * DHEAD + dh,
                       &As[(bf ^ 1) * 2048 + srow * 32 + scol]);
            #pragma unroll
            for (int half = 0; half < 2; half++) {
                const int row = srow + half * 64;
                load16_lds(B + (size_t)(n0 + row) * DMODEL + k0 + scol,
                           &Bs[(bf ^ 1) * 4096 + row * 32 + scol]);
            }
        }
        const int oa = bf * 2048, ob_ = bf * 4096;
        bf16x8 af[2], bfr[4];
        #pragma unroll
        for (int s = 0; s < 2; s++)
            af[s] = *reinterpret_cast<const bf16x8*>(
                &As[oa + (wm + s * 16 + l16) * 32 + quad * 8]);
        #pragma unroll
        for (int s = 0; s < 4; s++)
            bfr[s] = *reinterpret_cast<const bf16x8*>(
                &Bs[ob_ + (wn + s * 16 + l16) * 32 + quad * 8]);
        #pragma unroll
        for (int i = 0; i < 2; i++)
            #pragma unroll
            for (int j = 0; j < 4; j++)
                acc[i][j] = __builtin_amdgcn_mfma_f32_16x16x32_bf16(
                    af[i], bfr[j], acc[i][j], 0, 0, 0);
    }
    #pragma unroll
    for (int i = 0; i < 2; i++)
        #pragma unroll
        for (int r = 0; r < 4; r++) {
            const int m = m0 + wm + i * 16 + quad * 4 + r;
            #pragma unroll
            for (int j = 0; j < 4; j++)
                C[(size_t)m * DMODEL + n0 + wn + j * 16 + l16] = acc[i][j][r];
        }
}

// ---------------------------------------------------------------------------
// MFMA flash attention v7: K-fragments DIRECT FROM GLOBAL (L2-resident,
// natural b128 per frag — no staging, no LDS read); V LDS-staged with
// single-barrier async-DMA double-buffer; max-free exp2 softmax.
// LDS 26 KB -> 4 blocks/CU (grid 1024 = 4/CU) to hide the ~200-cyc L2 latency.
// ---------------------------------------------------------------------------
__global__ __launch_bounds__(256)
void attn_mfma7(const ushort* __restrict__ qb, const ushort* __restrict__ kb,
                const ushort* __restrict__ vtg, ushort* __restrict__ ob) {
    __shared__ __align__(16) ushort Vs[2][4096];   // [buf][feat*64 + slot*8]
    __shared__ ushort Pb[4][16][72];               // [wave][q][key]

    const int bh   = blockIdx.x;
    const int b    = bh >> 4;
    const int h    = bh & 15;
    const int qt   = (gridDim.y - 1) - blockIdx.y;   // heavy blocks first
    const int tid  = threadIdx.x;
    const int w    = tid >> 6;
    const int lane = tid & 63;
    const int l16  = lane & 15;
    const int quad = lane >> 4;
    const size_t base = (size_t)bh * SEQ * DHEAD;

    const int qlo = qt * 64 + w * 16;

    // Q fragments (B operand), pre-scaled by (1/8)*log2(e): exp2-domain scores
    const float SC = 0.125f * 1.44269504088896f;
    bf16x8 qa[2];
    {
        const size_t qo = base + (size_t)(qlo + l16) * DHEAD + quad * 8;
        qa[0] = *reinterpret_cast<const bf16x8*>(qb + qo);
        qa[1] = *reinterpret_cast<const bf16x8*>(qb + qo + 32);
        #pragma unroll
        for (int j = 0; j < 8; j++) {
            qa[0][j] = (__bf16)(SC * (float)qa[0][j]);
            qa[1][j] = (__bf16)(SC * (float)qa[1][j]);
        }
    }

    f32x4 oacc[4];
    #pragma unroll
    for (int s = 0; s < 4; s++) oacc[s] = (f32x4){0.f, 0.f, 0.f, 0.f};
    float l_ = 0.f;

    // --- V staging (async DMA, XOR-swizzled chunks) ---
    const int c0 = tid,        r0 = c0 >> 3, g0 = (c0 & 7) ^ (r0 & 7);
    const int c1 = 256 + tid,  r1 = c1 >> 3, g1 = (c1 & 7) ^ (r1 & 7);
    const ushort* vg0 = vtg + (size_t)(h * DHEAD + r0) * MROWS + b * SEQ + g0 * 8;
    const ushort* vg1 = vtg + (size_t)(h * DHEAD + r1) * MROWS + b * SEQ + g1 * 8;

    // --- V fragment read offsets (swizzle folded in) ---
    int voff[2][4];
    #pragma unroll
    for (int half = 0; half < 2; half++)
        #pragma unroll
        for (int sub = 0; sub < 4; sub++)
            voff[half][sub] = (sub * 16 + l16) * 64 +
                              (((half * 4 + quad) ^ (l16 & 7)) * 8);

    // --- K fragment base: direct global b128 per (key-block, d-chunk) ---
    const ushort* kfb = kb + base + (size_t)l16 * DHEAD + quad * 8;

    // prologue: stage V tile 0 into buffer 0
    load16_lds(vg0, &Vs[0][c0 * 8]);
    load16_lds(vg1, &Vs[0][c1 * 8]);

    const int T = qt + 1;
    for (int t = 0; t < T; t++) {
        const int bf = t & 1;
        __syncthreads();   // vmcnt drain: Vs[bf] landed; reads of Vs[bf^1] done
        if (t + 1 < T) {
            const int vo = (t + 1) * 64;
            load16_lds(vg0 + vo, &Vs[bf ^ 1][c0 * 8]);
            load16_lds(vg1 + vo, &Vs[bf ^ 1][c1 * 8]);
        }

        const bool diag = (t == qt);
        const int nsub = diag ? (w + 1) : 4;          // wave-uniform
        const int nhv  = diag ? ((w >> 1) + 1) : 2;   // wave-uniform

        // ---- K frags straight from global (L2) ----
        bf16x8 kf[2][4];
        #pragma unroll
        for (int half = 0; half < 2; half++)
            #pragma unroll
            for (int sub = 0; sub < 4; sub++)
                if (sub < nsub)
                    kf[half][sub] = *reinterpret_cast<const bf16x8*>(
                        kfb + (size_t)(t * 64 + sub * 16) * DHEAD + half * 32);

        // ---- S^T = K Q^T ----
        f32x4 sacc[4];
        #pragma unroll
        for (int s = 0; s < 4; s++) sacc[s] = (f32x4){0.f, 0.f, 0.f, 0.f};
        #pragma unroll
        for (int half = 0; half < 2; half++)
            #pragma unroll
            for (int sub = 0; sub < 4; sub++)
                if (sub < nsub)
                    sacc[sub] = __builtin_amdgcn_mfma_f32_16x16x32_bf16(
                        kf[half][sub], qa[half], sacc[sub], 0, 0, 0);

        // ---- max-free softmax ----
        float ev[4][4];
        if (diag) {
            const int thr = qlo + l16 - t * 64;
            #pragma unroll
            for (int sub = 0; sub < 4; sub++)
                #pragma unroll
                for (int r = 0; r < 4; r++) {
                    const float e = (sub * 16 + quad * 4 + r <= thr)
                                        ? exp2f(sacc[sub][r]) : 0.f;
                    ev[sub][r] = e;
                    l_ += e;
                }
        } else {
            #pragma unroll
            for (int sub = 0; sub < 4; sub++)
                #pragma unroll
                for (int r = 0; r < 4; r++) {
                    const float e = exp2f(sacc[sub][r]);
                    ev[sub][r] = e;
                    l_ += e;
                }
        }

        // ---- P -> LDS (bf16) -> A-frag, wave-private ----
        #pragma unroll
        for (int sub = 0; sub < 4; sub++) {
            ushort4 pk;
            pk.x = bf16u(ev[sub][0]); pk.y = bf16u(ev[sub][1]);
            pk.z = bf16u(ev[sub][2]); pk.w = bf16u(ev[sub][3]);
            *reinterpret_cast<ushort4*>(&Pb[w][l16][sub * 16 + quad * 4]) = pk;
        }
        bf16x8 pa[2];
        pa[0] = *reinterpret_cast<const bf16x8*>(&Pb[w][l16][quad * 8]);
        pa[1] = *reinterpret_cast<const bf16x8*>(&Pb[w][l16][32 + quad * 8]);

        // ---- O += P V ----
        #pragma unroll
        for (int hk = 0; hk < 2; hk++) {
            if (hk >= nhv) break;
            #pragma unroll
            for (int sf = 0; sf < 4; sf++) {
                const bf16x8 vf = *reinterpret_cast<const bf16x8*>(
                    &Vs[bf][voff[hk][sf]]);
                oacc[sf] = __builtin_amdgcn_mfma_f32_16x16x32_bf16(
                    pa[hk], vf, oacc[sf], 0, 0, 0);
            }
        }
    }

    // epilogue: reduce l across quads, normalize
    l_ += __shfl_xor(l_, 16, 64);
    l_ += __shfl_xor(l_, 32, 64);
    float inv[4];
    #pragma unroll
    for (int r = 0; r < 4; r++) inv[r] = 1.f / __shfl(l_, quad * 4 + r, 64);
    #pragma unroll
    for (int sub = 0; sub < 4; sub++)
        #pragma unroll
        for (int r = 0; r < 4; r++) {
            const int q = qlo + quad * 4 + r;
            ob[base + (size_t)q * DHEAD + sub * 16 + l16] =
                bf16u(oacc[sub][r] * inv[r]);
        }
}

// ---------------------------------------------------------------------------
extern "C" void kernel_launch(void* const* d_in, const int* in_sizes, int n_in,
                              void* d_out, int out_size, void* d_ws, size_t ws_size,
                              hipStream_t stream) {
    const float* x  = (const float*)d_in[0];
    const float* Wq = (const float*)d_in[1];
    const float* Wk = (const float*)d_in[2];
    const float* Wv = (const float*)d_in[3];
    const float* Wo = (const float*)d_in[4];
    const int* pos = (const int*)d_in[5];

    const size_t TEN = (size_t)MROWS * DMODEL;   // 4M elements
    const size_t WEL = (size_t)DMODEL * DMODEL;  // 1M elements
    ushort* xb   = (ushort*)d_ws;      // 8 MB
    ushort* Wqkv = xb + TEN;           // 8 MB (Wq,Wk,Wv,Wo contiguous)
    ushort* Wob  = Wqkv + 3 * WEL;
    ushort* qb   = Wob + WEL;          // 8 MB each; kb, vtb contiguous
    ushort* kb   = qb + TEN;
    ushort* vtb  = kb + TEN;           // V^T [1024][4096]
    ushort* ob   = vtb + TEN;
    float2* tab  = (float2*)(ob + TEN);  // 512 KB rope table

    dim3 blk(256);
    prep<<<4352, blk, 0, stream>>>(x, Wq, Wk, Wv, Wo, pos, xb, Wqkv, tab);

    dim3 gqkv(3 * DMODEL / 128, MROWS / 128);   // (24, 32)
    gemm_qkv<<<gqkv, blk, 0, stream>>>(xb, Wqkv, qb, tab);

    dim3 gattn(BATCH * NHEAD, SEQ / 64);        // (32, 32)
    attn_mfma7<<<gattn, blk, 0, stream>>>(qb, kb, vtb, ob);

    dim3 gout(DMODEL / 128, MROWS / 64);        // (8, 64)
    gemm_out64<<<gout, blk, 0, stream>>>(ob, Wob, (float*)d_out);
}